// Round 3
// 105.713 us; speedup vs baseline: 1.0130x; 1.0130x over previous
//
#include <hip/hip_runtime.h>
#include <hip/hip_bf16.h>

#define B_DIM 256
#define I_DIM 128
#define O_DIM 128
#define H_DIM 32
#define F_DIM 7
#define ICHUNK 8
#define NCHUNK (I_DIM / ICHUNK)   // 16
#define NLOG2E -1.4426950408889634f
#define NLN2   -0.6931471805599453f

typedef __attribute__((ext_vector_type(8))) short short8;   // 8 bf16 (4 VGPRs)
typedef __attribute__((ext_vector_type(4))) float float4v;  // MFMA C/D

__device__ inline short bf16s(float v) {
    union { __hip_bfloat16 h; short s; } u;
    u.h = __float2bfloat16(v);
    return u.s;
}

// exp2 via compiler-visible op. R14 LESSON: raw `asm("v_exp_f32")` reading an
// MFMA result register skips the hazard recognizer's MFMA->VALU wait-states
// (INLINEASM consumer is opaque) -> sporadic corruption, absmax 7.39. The
// builtin keeps producer+consumer visible so required s_nops are inserted.
__device__ inline float exp2_fast(float u) {
#if __has_builtin(__builtin_amdgcn_exp2f)
    return __builtin_amdgcn_exp2f(u);
#else
    return exp2f(u);
#endif
}

__device__ inline short8 feat_pack(float xv) {
    float s1 = __sinf(xv), c1 = __cosf(xv);
    float s2 = 2.f * s1 * c1, c2 = 1.f - 2.f * s1 * s1;
    float s4 = 2.f * s2 * c2, c4 = 1.f - 2.f * s2 * s2;
    short8 a;
    a[0] = bf16s(xv); a[1] = bf16s(s1); a[2] = bf16s(s2); a[3] = bf16s(s4);
    a[4] = bf16s(c1); a[5] = bf16s(c2); a[6] = bf16s(c4); a[7] = 0;
    return a;
}

// R14/R15 pre-kernel: pack features ONCE for all (i,b) -> feat_g[i][b] (16B
// each, 512 KB, L2-resident). Previously every one of the 2048 main blocks
// recomputed trig for its 256x8 slice (128x redundant) AND burned 32 KB of
// LDS staging it — that LDS was the occupancy cap (4 blocks/CU).
__global__ __launch_bounds__(256)
void feat_kernel(const float* __restrict__ x, short* __restrict__ feat_g) {
    const int i = blockIdx.x;       // 128 blocks
    const int b = threadIdx.x;      // 256 threads
    float xv = x[(size_t)b * I_DIM + i];   // x is 128 KB, L2-resident
    *reinterpret_cast<short8*>(feat_g + ((size_t)i * B_DIM + b) * 8) = feat_pack(xv);
}

// Main kernel: A-fragments come straight from feat_g (L1-hit, 4 q-lanes
// broadcast the same 16B row). LDS is only the per-(o,chunk) W1/B1/W2
// staging (6 KB) -> __launch_bounds__(256,6) = 6 blocks/CU (was 4 with the
// 38 KB LDS footprint), VGPR cap ~80 (demand ~60-70, no spill).
//
// exp2 folding: W1,B1 pre-scaled by -log2(e) at staging so the MFMA emits
// u = -log2e*z; sigma(z) = rcp(1 + exp2(u)) with NO per-element scaling mul.
// W2 pre-scaled by -ln2 so acc += (u*sigma)*w2' == z*sigma*W2 exactly
// (log2e * ln2 == 1). Saves 1 VALU op per silu element.
//
// REGISTER-PRESSURE LAW (R2/R4/R5): il-loop kept rolled (unroll 1): full
// unroll multiplies live ranges; occupancy does the latency hiding now.
__global__ __launch_bounds__(256, 6)
void fcnkan_ws(const short* __restrict__ feat_g,
               const float* __restrict__ W1,
               const float* __restrict__ W2,
               const float* __restrict__ B1,
               const float* __restrict__ B2,
               float* __restrict__ ws) {
    __shared__ __align__(16) short w1_s[ICHUNK * H_DIM * 8];     // 4 KB
    __shared__ float b1_s[ICHUNK * H_DIM];                       // 1 KB
    __shared__ float w2_s[ICHUNK * H_DIM];                       // 1 KB

    const int tid  = threadIdx.x;
    const int o    = blockIdx.x;
    const int ic0  = blockIdx.y * ICHUNK;
    const int w    = tid >> 6;       // wave: b-range [w*64, w*64+64)
    const int lane = tid & 63;
    const int m    = lane & 15;      // row/col within 16x16 tile
    const int q    = lane >> 4;      // quad

    const short8 zero8 = {};

    // ---- stage B: thread tid <-> (il = tid>>5, h = tid&31), one W1 row ----
    {
        int il = tid >> 5, h = tid & 31;
        size_t iobase = (size_t)(ic0 + il) * O_DIM + o;
        const float* wr = W1 + iobase * (H_DIM * F_DIM) + h * F_DIM;
        short8 bfr;
        #pragma unroll
        for (int f = 0; f < F_DIM; ++f) bfr[f] = bf16s(wr[f] * NLOG2E);
        bfr[7] = 0;
        *reinterpret_cast<short8*>(w1_s + tid * 8) = bfr;
        b1_s[tid] = B1[iobase * H_DIM + h] * NLOG2E;
        w2_s[tid] = W2[iobase * H_DIM + h] * NLN2;
    }
    __syncthreads();

    float acc[16];
    #pragma unroll
    for (int r = 0; r < 16; ++r) acc[r] = 0.f;

    #pragma unroll 1
    for (int il = 0; il < ICHUNK; ++il) {
        const short8* fG = reinterpret_cast<const short8*>(feat_g)
                           + (size_t)(ic0 + il) * B_DIM;
        const short8* wS = reinterpret_cast<const short8*>(w1_s) + il * H_DIM;

        short8 afrag[4];
        #pragma unroll
        for (int t = 0; t < 4; ++t)
            afrag[t] = fG[w * 64 + t * 16 + m];          // global_load_dwordx4, L1-hit

        short8 bfrag[2];
        float  b1v[2], w2v[2];
        #pragma unroll
        for (int nt = 0; nt < 2; ++nt) {
            int h = nt * 16 + m;
            short8 b = wS[h];                            // ds_read_b128
            bfrag[nt] = (q == 0) ? b : zero8;            // only B quad-zeroed
            b1v[nt] = b1_s[il * H_DIM + h];
            w2v[nt] = w2_s[il * H_DIM + h];
        }

        #pragma unroll
        for (int nt = 0; nt < 2; ++nt) {
            float4v c0 = {b1v[nt], b1v[nt], b1v[nt], b1v[nt]};
            #pragma unroll
            for (int t = 0; t < 4; ++t) {
                float4v z = __builtin_amdgcn_mfma_f32_16x16x32_bf16(
                    afrag[t], bfrag[nt], c0, 0, 0, 0);
                #pragma unroll
                for (int r = 0; r < 4; ++r) {
                    float u = z[r];                      // u = -log2e * zpre
                    float e = exp2_fast(u);              // e = exp(-zpre)
                    float sg = __builtin_amdgcn_rcpf(1.f + e);   // sigma(zpre)
                    acc[t * 4 + r] = fmaf(u * sg, w2v[nt], acc[t * 4 + r]);
                }
            }
        }
    }

    // ---- h-sum: butterfly over the 16 lanes of each quad-group ----
    #pragma unroll
    for (int r = 0; r < 16; ++r) {
        float v = acc[r];
        v += __shfl_xor(v, 1, 64);
        v += __shfl_xor(v, 2, 64);
        v += __shfl_xor(v, 4, 64);
        v += __shfl_xor(v, 8, 64);
        acc[r] = v;
    }

    // per-chunk B2 contribution (uniform)
    float b2c = 0.f;
    for (int il = 0; il < ICHUNK; ++il) b2c += B2[(size_t)(ic0 + il) * O_DIM + o];

    // lane m==0 of each quad-group writes its 16 rows (plain stores; the
    // block covers a contiguous 1 KB ws slice -> L2 coalesces the lines)
    if (m == 0) {
        float* wsp = ws + ((size_t)blockIdx.y * O_DIM + o) * B_DIM;
        #pragma unroll
        for (int t = 0; t < 4; ++t)
            #pragma unroll
            for (int r = 0; r < 4; ++r)
                wsp[w * 64 + t * 16 + q * 4 + r] = acc[t * 4 + r] + b2c;
    }
}

// Sum the NCHUNK partials per (o,b). Reads coalesced (256 consecutive
// floats per chunk per block); 2 MB total, L2-resident.
__global__ __launch_bounds__(256)
void reduce_kernel(const float* __restrict__ ws, float* __restrict__ out) {
    const int o = blockIdx.x;
    const int b = threadIdx.x;
    float s = 0.f;
    #pragma unroll
    for (int c = 0; c < NCHUNK; ++c)
        s += ws[((size_t)c * O_DIM + o) * B_DIM + b];
    out[(size_t)b * O_DIM + o] = s;
}

// Fallback (ws too small): R13 atomic path verbatim — in-kernel staging,
// original silu numerics, atomicAdd into memset-zeroed out.
__global__ __launch_bounds__(256, 2)
void fcnkan_atomic(const float* __restrict__ x,
                   const float* __restrict__ W1,
                   const float* __restrict__ W2,
                   const float* __restrict__ B1,
                   const float* __restrict__ B2,
                   float* __restrict__ out) {
    __shared__ __align__(16) short feat_s[ICHUNK * B_DIM * 8];   // 32 KB
    __shared__ __align__(16) short w1_s[ICHUNK * H_DIM * 8];     // 4 KB
    __shared__ float b1_s[ICHUNK * H_DIM];                       // 1 KB
    __shared__ float w2_s[ICHUNK * H_DIM];                       // 1 KB

    const int tid  = threadIdx.x;
    const int o    = blockIdx.x;
    const int ic0  = blockIdx.y * ICHUNK;
    const int w    = tid >> 6;
    const int lane = tid & 63;
    const int m    = lane & 15;
    const int q    = lane >> 4;

    const short8 zero8 = {};

    {
        const float4* xp = reinterpret_cast<const float4*>(x + (size_t)tid * I_DIM + ic0);
        float4 x0 = xp[0], x1 = xp[1];
        float xr[8] = {x0.x, x0.y, x0.z, x0.w, x1.x, x1.y, x1.z, x1.w};
        #pragma unroll
        for (int il = 0; il < ICHUNK; ++il)
            *reinterpret_cast<short8*>(feat_s + (il * B_DIM + tid) * 8) = feat_pack(xr[il]);
    }
    {
        int il = tid >> 5, h = tid & 31;
        size_t iobase = (size_t)(ic0 + il) * O_DIM + o;
        const float* wr = W1 + iobase * (H_DIM * F_DIM) + h * F_DIM;
        short8 bfr;
        #pragma unroll
        for (int f = 0; f < F_DIM; ++f) bfr[f] = bf16s(wr[f]);
        bfr[7] = 0;
        *reinterpret_cast<short8*>(w1_s + tid * 8) = bfr;
        b1_s[tid] = B1[iobase * H_DIM + h];
        w2_s[tid] = W2[iobase * H_DIM + h];
    }
    __syncthreads();

    float acc[16];
    #pragma unroll
    for (int r = 0; r < 16; ++r) acc[r] = 0.f;

    #pragma unroll 1
    for (int il = 0; il < ICHUNK; ++il) {
        const short8* fS = reinterpret_cast<const short8*>(feat_s) + il * B_DIM;
        const short8* wS = reinterpret_cast<const short8*>(w1_s) + il * H_DIM;

        short8 afrag[4];
        #pragma unroll
        for (int t = 0; t < 4; ++t)
            afrag[t] = fS[w * 64 + t * 16 + m];

        short8 bfrag[2];
        float  b1v[2], w2v[2];
        #pragma unroll
        for (int nt = 0; nt < 2; ++nt) {
            int h = nt * 16 + m;
            short8 b = wS[h];
            bfrag[nt] = (q == 0) ? b : zero8;
            b1v[nt] = b1_s[il * H_DIM + h];
            w2v[nt] = w2_s[il * H_DIM + h];
        }

        #pragma unroll
        for (int nt = 0; nt < 2; ++nt) {
            float4v c0 = {b1v[nt], b1v[nt], b1v[nt], b1v[nt]};
            #pragma unroll
            for (int t = 0; t < 4; ++t) {
                float4v z = __builtin_amdgcn_mfma_f32_16x16x32_bf16(
                    afrag[t], bfrag[nt], c0, 0, 0, 0);
                #pragma unroll
                for (int r = 0; r < 4; ++r) {
                    float zz = z[r];
                    float sg = __builtin_amdgcn_rcpf(1.f + __expf(-zz));
                    acc[t * 4 + r] = fmaf(zz * sg, w2v[nt], acc[t * 4 + r]);
                }
            }
        }
    }

    #pragma unroll
    for (int r = 0; r < 16; ++r) {
        float v = acc[r];
        v += __shfl_xor(v, 1, 64);
        v += __shfl_xor(v, 2, 64);
        v += __shfl_xor(v, 4, 64);
        v += __shfl_xor(v, 8, 64);
        acc[r] = v;
    }

    float b2c = 0.f;
    for (int il = 0; il < ICHUNK; ++il) b2c += B2[(size_t)(ic0 + il) * O_DIM + o];

    if (m == 0) {
        #pragma unroll
        for (int t = 0; t < 4; ++t)
            #pragma unroll
            for (int r = 0; r < 4; ++r) {
                int b = w * 64 + t * 16 + q * 4 + r;
                atomicAdd(&out[(size_t)b * O_DIM + o], acc[t * 4 + r] + b2c);
            }
    }
}

extern "C" void kernel_launch(void* const* d_in, const int* in_sizes, int n_in,
                              void* d_out, int out_size, void* d_ws, size_t ws_size,
                              hipStream_t stream) {
    const float* x  = (const float*)d_in[0];
    const float* W1 = (const float*)d_in[1];
    const float* W2 = (const float*)d_in[2];
    const float* B1 = (const float*)d_in[3];
    const float* B2 = (const float*)d_in[4];
    float* out = (float*)d_out;
    float* ws  = (float*)d_ws;

    const size_t part_bytes = (size_t)NCHUNK * O_DIM * B_DIM * sizeof(float); // 2 MiB
    const size_t feat_bytes = (size_t)I_DIM * B_DIM * 8 * sizeof(short);      // 512 KiB
    const size_t ws_need = part_bytes + feat_bytes;                           // 2.5 MiB

    dim3 grid(O_DIM, NCHUNK);
    if (ws_size >= ws_need) {   // launch-invariant -> graph-safe
        short* feat_g = (short*)((char*)d_ws + part_bytes);
        feat_kernel<<<I_DIM, B_DIM, 0, stream>>>(x, feat_g);
        fcnkan_ws<<<grid, 256, 0, stream>>>(feat_g, W1, W2, B1, B2, ws);
        reduce_kernel<<<O_DIM, B_DIM, 0, stream>>>(ws, out);
    } else {
        hipMemsetAsync(out, 0, (size_t)out_size * sizeof(float), stream);
        fcnkan_atomic<<<grid, 256, 0, stream>>>(x, W1, W2, B1, B2, out);
    }
}

// Round 4
// 104.318 us; speedup vs baseline: 1.0265x; 1.0134x over previous
//
#include <hip/hip_runtime.h>
#include <hip/hip_bf16.h>

#define B_DIM 256
#define I_DIM 128
#define O_DIM 128
#define H_DIM 32
#define F_DIM 7
#define ICHUNK 8
#define NCHUNK (I_DIM / ICHUNK)   // 16
#define NLOG2E -1.4426950408889634f
#define NLN2   -0.6931471805599453f

typedef __attribute__((ext_vector_type(8))) short short8;   // 8 bf16 (4 VGPRs)
typedef __attribute__((ext_vector_type(4))) float float4v;  // MFMA C/D
typedef __attribute__((ext_vector_type(2))) float float2v;  // packed f32 pair

__device__ inline short bf16s(float v) {
    union { __hip_bfloat16 h; short s; } u;
    u.h = __float2bfloat16(v);
    return u.s;
}

// exp2 via compiler-visible op. R14 LESSON: raw `asm("v_exp_f32")` reading an
// MFMA result register skips the hazard recognizer's MFMA->VALU wait-states
// (INLINEASM consumer is opaque) -> sporadic corruption, absmax 7.39. The
// builtin keeps producer+consumer visible so required s_nops are inserted.
// (R15 verified correct: absmax 0.125.)
__device__ inline float exp2_fast(float u) {
#if __has_builtin(__builtin_amdgcn_exp2f)
    return __builtin_amdgcn_exp2f(u);
#else
    return exp2f(u);
#endif
}

__device__ inline short8 feat_pack(float xv) {
    float s1 = __sinf(xv), c1 = __cosf(xv);
    float s2 = 2.f * s1 * c1, c2 = 1.f - 2.f * s1 * s1;
    float s4 = 2.f * s2 * c2, c4 = 1.f - 2.f * s2 * s2;
    short8 a;
    a[0] = bf16s(xv); a[1] = bf16s(s1); a[2] = bf16s(s2); a[3] = bf16s(s4);
    a[4] = bf16s(c1); a[5] = bf16s(c2); a[6] = bf16s(c4); a[7] = 0;
    return a;
}

// Pre-kernel: pack features ONCE for all (i,b) -> feat_g[i][b] (16B each,
// 512 KB, L2-resident). Dedups the 128x-redundant per-block trig and frees
// the 32 KB LDS that capped occupancy through R13.
__global__ __launch_bounds__(256)
void feat_kernel(const float* __restrict__ x, short* __restrict__ feat_g) {
    const int i = blockIdx.x;       // 128 blocks
    const int b = threadIdx.x;      // 256 threads
    float xv = x[(size_t)b * I_DIM + i];   // x is 128 KB, L2-resident
    *reinterpret_cast<short8*>(feat_g + ((size_t)i * B_DIM + b) * 8) = feat_pack(xv);
}

// R16 main kernel: 128-thread blocks (2 waves), grid (o, chunk, b-half) =
// 4096 blocks. R13 showed 30% occupancy against a 50% residency cap — the
// gap was TAIL DILUTION (8 coarse blocks/CU of work, 6 resident -> ragged
// 6+2 schedule). Halving the block halves the scheduling quantum; per-wave
// instruction stream is identical (each wave still owns 64 b-rows).
// __launch_bounds__(128,7): 7 waves/EU -> 14 blocks = 28 waves/CU (87.5%
// cap), VGPR cap 73 vs demand ~60 (R13 counter) — no spill.
//
// exp2 folding (R15-verified): W1,B1 pre-scaled by -log2e, W2 by -ln2;
// u = MFMA output = -log2e*z; silu(z)*W2 = (u*rcp(1+exp2(u)))*w2'.
// Silu arithmetic processed as float2 pairs to invite v_pk_{add,mul,fma}_f32
// (halves issue slots on the full-rate ops; trans stays scalar).
__global__ __launch_bounds__(128, 7)
void fcnkan_ws(const short* __restrict__ feat_g,
               const float* __restrict__ W1,
               const float* __restrict__ W2,
               const float* __restrict__ B1,
               const float* __restrict__ B2,
               float* __restrict__ ws) {
    __shared__ __align__(16) short w1_s[ICHUNK * H_DIM * 8];     // 4 KB
    __shared__ float b1_s[ICHUNK * H_DIM];                       // 1 KB
    __shared__ float w2_s[ICHUNK * H_DIM];                       // 1 KB

    const int tid  = threadIdx.x;    // 0..127
    const int o    = blockIdx.x;
    const int ic0  = blockIdx.y * ICHUNK;
    const int bh   = blockIdx.z;     // b-half: rows [bh*128, bh*128+128)
    const int w    = tid >> 6;       // wave in block: 0/1
    const int lane = tid & 63;
    const int m    = lane & 15;      // row/col within 16x16 tile
    const int q    = lane >> 4;      // quad
    const int brow = bh * 128 + w * 64;   // this wave's 64-row b-base

    const short8 zero8 = {};

    // ---- stage B: 128 threads stage 256 (il,h) W1 rows: 2 per thread ----
    #pragma unroll
    for (int s = 0; s < 2; ++s) {
        int idx = s * 128 + tid;         // 0..255
        int il = idx >> 5, h = idx & 31;
        size_t iobase = (size_t)(ic0 + il) * O_DIM + o;
        const float* wr = W1 + iobase * (H_DIM * F_DIM) + h * F_DIM;
        short8 bfr;
        #pragma unroll
        for (int f = 0; f < F_DIM; ++f) bfr[f] = bf16s(wr[f] * NLOG2E);
        bfr[7] = 0;
        *reinterpret_cast<short8*>(w1_s + idx * 8) = bfr;
        b1_s[idx] = B1[iobase * H_DIM + h] * NLOG2E;
        w2_s[idx] = W2[iobase * H_DIM + h] * NLN2;
    }
    __syncthreads();

    float2v acc2[8];                 // acc[t*4+r] pairs: acc2[t*2 + r/2]
    #pragma unroll
    for (int p = 0; p < 8; ++p) acc2[p] = (float2v){0.f, 0.f};

    #pragma unroll 1
    for (int il = 0; il < ICHUNK; ++il) {
        const short8* fG = reinterpret_cast<const short8*>(feat_g)
                           + (size_t)(ic0 + il) * B_DIM;
        const short8* wS = reinterpret_cast<const short8*>(w1_s) + il * H_DIM;

        short8 afrag[4];
        #pragma unroll
        for (int t = 0; t < 4; ++t)
            afrag[t] = fG[brow + t * 16 + m];            // global_load_dwordx4, L1/L2-hit

        short8 bfrag[2];
        float  b1v[2], w2v[2];
        #pragma unroll
        for (int nt = 0; nt < 2; ++nt) {
            int h = nt * 16 + m;
            short8 b = wS[h];                            // ds_read_b128
            bfrag[nt] = (q == 0) ? b : zero8;            // only B quad-zeroed
            b1v[nt] = b1_s[il * H_DIM + h];
            w2v[nt] = w2_s[il * H_DIM + h];
        }

        #pragma unroll
        for (int nt = 0; nt < 2; ++nt) {
            float4v c0 = {b1v[nt], b1v[nt], b1v[nt], b1v[nt]};
            float2v w2p = {w2v[nt], w2v[nt]};
            #pragma unroll
            for (int t = 0; t < 4; ++t) {
                float4v z = __builtin_amdgcn_mfma_f32_16x16x32_bf16(
                    afrag[t], bfrag[nt], c0, 0, 0, 0);
                #pragma unroll
                for (int r = 0; r < 4; r += 2) {
                    float2v u = {z[r], z[r + 1]};        // u = -log2e * zpre
                    float2v e = {exp2_fast(u.x), exp2_fast(u.y)};  // exp(-zpre)
                    float2v d = u;                        // keep u live
                    float2v s = e + 1.f;                  // v_pk_add_f32
                    float2v sg = {__builtin_amdgcn_rcpf(s.x),
                                  __builtin_amdgcn_rcpf(s.y)};
                    float2v p = d * sg;                   // v_pk_mul_f32
                    acc2[t * 2 + (r >> 1)] = p * w2p + acc2[t * 2 + (r >> 1)];
                }
            }
        }
    }

    // ---- h-sum: butterfly over the 16 lanes of each quad-group ----
    float acc[16];
    #pragma unroll
    for (int t = 0; t < 4; ++t) {
        acc[t * 4 + 0] = acc2[t * 2 + 0].x;
        acc[t * 4 + 1] = acc2[t * 2 + 0].y;
        acc[t * 4 + 2] = acc2[t * 2 + 1].x;
        acc[t * 4 + 3] = acc2[t * 2 + 1].y;
    }
    #pragma unroll
    for (int r = 0; r < 16; ++r) {
        float v = acc[r];
        v += __shfl_xor(v, 1, 64);
        v += __shfl_xor(v, 2, 64);
        v += __shfl_xor(v, 4, 64);
        v += __shfl_xor(v, 8, 64);
        acc[r] = v;
    }

    // per-chunk B2 contribution (uniform)
    float b2c = 0.f;
    for (int il = 0; il < ICHUNK; ++il) b2c += B2[(size_t)(ic0 + il) * O_DIM + o];

    // lane m==0 of each quad-group writes its 16 rows (plain stores; the
    // block covers a contiguous 512B ws slice -> L2 coalesces the lines)
    if (m == 0) {
        float* wsp = ws + ((size_t)blockIdx.y * O_DIM + o) * B_DIM;
        #pragma unroll
        for (int t = 0; t < 4; ++t)
            #pragma unroll
            for (int r = 0; r < 4; ++r)
                wsp[brow + t * 16 + q * 4 + r] = acc[t * 4 + r] + b2c;
    }
}

// Sum the NCHUNK partials per (o,b). Reads coalesced (256 consecutive
// floats per chunk per block); 2 MB total, L2-resident.
__global__ __launch_bounds__(256)
void reduce_kernel(const float* __restrict__ ws, float* __restrict__ out) {
    const int o = blockIdx.x;
    const int b = threadIdx.x;
    float s = 0.f;
    #pragma unroll
    for (int c = 0; c < NCHUNK; ++c)
        s += ws[((size_t)c * O_DIM + o) * B_DIM + b];
    out[(size_t)b * O_DIM + o] = s;
}

// Fallback (ws too small): R13 atomic path verbatim — in-kernel staging,
// original silu numerics, atomicAdd into memset-zeroed out.
__global__ __launch_bounds__(256, 2)
void fcnkan_atomic(const float* __restrict__ x,
                   const float* __restrict__ W1,
                   const float* __restrict__ W2,
                   const float* __restrict__ B1,
                   const float* __restrict__ B2,
                   float* __restrict__ out) {
    __shared__ __align__(16) short feat_s[ICHUNK * B_DIM * 8];   // 32 KB
    __shared__ __align__(16) short w1_s[ICHUNK * H_DIM * 8];     // 4 KB
    __shared__ float b1_s[ICHUNK * H_DIM];                       // 1 KB
    __shared__ float w2_s[ICHUNK * H_DIM];                       // 1 KB

    const int tid  = threadIdx.x;
    const int o    = blockIdx.x;
    const int ic0  = blockIdx.y * ICHUNK;
    const int w    = tid >> 6;
    const int lane = tid & 63;
    const int m    = lane & 15;
    const int q    = lane >> 4;

    const short8 zero8 = {};

    {
        const float4* xp = reinterpret_cast<const float4*>(x + (size_t)tid * I_DIM + ic0);
        float4 x0 = xp[0], x1 = xp[1];
        float xr[8] = {x0.x, x0.y, x0.z, x0.w, x1.x, x1.y, x1.z, x1.w};
        #pragma unroll
        for (int il = 0; il < ICHUNK; ++il)
            *reinterpret_cast<short8*>(feat_s + (il * B_DIM + tid) * 8) = feat_pack(xr[il]);
    }
    {
        int il = tid >> 5, h = tid & 31;
        size_t iobase = (size_t)(ic0 + il) * O_DIM + o;
        const float* wr = W1 + iobase * (H_DIM * F_DIM) + h * F_DIM;
        short8 bfr;
        #pragma unroll
        for (int f = 0; f < F_DIM; ++f) bfr[f] = bf16s(wr[f]);
        bfr[7] = 0;
        *reinterpret_cast<short8*>(w1_s + tid * 8) = bfr;
        b1_s[tid] = B1[iobase * H_DIM + h];
        w2_s[tid] = W2[iobase * H_DIM + h];
    }
    __syncthreads();

    float acc[16];
    #pragma unroll
    for (int r = 0; r < 16; ++r) acc[r] = 0.f;

    #pragma unroll 1
    for (int il = 0; il < ICHUNK; ++il) {
        const short8* fS = reinterpret_cast<const short8*>(feat_s) + il * B_DIM;
        const short8* wS = reinterpret_cast<const short8*>(w1_s) + il * H_DIM;

        short8 afrag[4];
        #pragma unroll
        for (int t = 0; t < 4; ++t)
            afrag[t] = fS[w * 64 + t * 16 + m];

        short8 bfrag[2];
        float  b1v[2], w2v[2];
        #pragma unroll
        for (int nt = 0; nt < 2; ++nt) {
            int h = nt * 16 + m;
            short8 b = wS[h];
            bfrag[nt] = (q == 0) ? b : zero8;
            b1v[nt] = b1_s[il * H_DIM + h];
            w2v[nt] = w2_s[il * H_DIM + h];
        }

        #pragma unroll
        for (int nt = 0; nt < 2; ++nt) {
            float4v c0 = {b1v[nt], b1v[nt], b1v[nt], b1v[nt]};
            #pragma unroll
            for (int t = 0; t < 4; ++t) {
                float4v z = __builtin_amdgcn_mfma_f32_16x16x32_bf16(
                    afrag[t], bfrag[nt], c0, 0, 0, 0);
                #pragma unroll
                for (int r = 0; r < 4; ++r) {
                    float zz = z[r];
                    float sg = __builtin_amdgcn_rcpf(1.f + __expf(-zz));
                    acc[t * 4 + r] = fmaf(zz * sg, w2v[nt], acc[t * 4 + r]);
                }
            }
        }
    }

    #pragma unroll
    for (int r = 0; r < 16; ++r) {
        float v = acc[r];
        v += __shfl_xor(v, 1, 64);
        v += __shfl_xor(v, 2, 64);
        v += __shfl_xor(v, 4, 64);
        v += __shfl_xor(v, 8, 64);
        acc[r] = v;
    }

    float b2c = 0.f;
    for (int il = 0; il < ICHUNK; ++il) b2c += B2[(size_t)(ic0 + il) * O_DIM + o];

    if (m == 0) {
        #pragma unroll
        for (int t = 0; t < 4; ++t)
            #pragma unroll
            for (int r = 0; r < 4; ++r) {
                int b = w * 64 + t * 16 + q * 4 + r;
                atomicAdd(&out[(size_t)b * O_DIM + o], acc[t * 4 + r] + b2c);
            }
    }
}

extern "C" void kernel_launch(void* const* d_in, const int* in_sizes, int n_in,
                              void* d_out, int out_size, void* d_ws, size_t ws_size,
                              hipStream_t stream) {
    const float* x  = (const float*)d_in[0];
    const float* W1 = (const float*)d_in[1];
    const float* W2 = (const float*)d_in[2];
    const float* B1 = (const float*)d_in[3];
    const float* B2 = (const float*)d_in[4];
    float* out = (float*)d_out;
    float* ws  = (float*)d_ws;

    const size_t part_bytes = (size_t)NCHUNK * O_DIM * B_DIM * sizeof(float); // 2 MiB
    const size_t feat_bytes = (size_t)I_DIM * B_DIM * 8 * sizeof(short);      // 512 KiB
    const size_t ws_need = part_bytes + feat_bytes;                           // 2.5 MiB

    if (ws_size >= ws_need) {   // launch-invariant -> graph-safe
        short* feat_g = (short*)((char*)d_ws + part_bytes);
        feat_kernel<<<I_DIM, B_DIM, 0, stream>>>(x, feat_g);
        dim3 grid(O_DIM, NCHUNK, 2);
        fcnkan_ws<<<grid, 128, 0, stream>>>(feat_g, W1, W2, B1, B2, ws);
        reduce_kernel<<<O_DIM, B_DIM, 0, stream>>>(ws, out);
    } else {
        hipMemsetAsync(out, 0, (size_t)out_size * sizeof(float), stream);
        dim3 grid(O_DIM, NCHUNK);
        fcnkan_atomic<<<grid, 256, 0, stream>>>(x, W1, W2, B1, B2, out);
    }
}